// Round 1
// 121.730 us; speedup vs baseline: 1.1670x; 1.1670x over previous
//
#include <hip/hip_runtime.h>

#define BN_EPS 1e-3f

typedef float vf4 __attribute__((ext_vector_type(4)));
typedef float f32x4 __attribute__((ext_vector_type(4)));
typedef _Float16 half8v __attribute__((ext_vector_type(8)));

// ---- order-preserving float<->uint key for atomicMax on floats ----
__device__ __forceinline__ unsigned int f2k(float f) {
    unsigned int u = __float_as_uint(f);
    return (u & 0x80000000u) ? ~u : (u | 0x80000000u);
}
__device__ __forceinline__ float k2f(unsigned int u) {
    return __uint_as_float((u & 0x80000000u) ? (u & 0x7FFFFFFFu) : ~u);
}

// Kernel 1: per-edge message via MFMA over the outer-product factorization
//   msg[e,h] = sum_k Z[e,k] * W[k,h],  K = S*F + F = 144 (padded to 160)
//   Z[e, s*F+f] = e[e,s] * x[src[e],f]    (generated in-register)
//   Z[e, S*F+f] = x[src[e],f]             (bias part, coeff 1)
//   W[s*F+f, h] = Wk[(s*F+f)*H+h];  W[S*F+f, h] = bk[f*H+h];  pad rows = 0
// One wave processes a 16-edge tile: 5 x mfma_f32_16x16x32_f16.
// C layout (verified): col = lane&15 (=h), row = (lane>>4)*4 + reg (=edge),
// which gives the coalesced 4-dstline x 16-channel atomic scatter directly —
// no LDS, no __syncthreads.
template <int S, int F, int H>
__global__ void __launch_bounds__(256)
edge_mfma(const float* __restrict__ efeat,
          const int* __restrict__ src,
          const int* __restrict__ dst,
          const float* __restrict__ x,
          const float* __restrict__ Wk,
          const float* __restrict__ bk,
          float* __restrict__ agg,
          int E) {
    const int lane = threadIdx.x & 63;
    const int g = lane >> 4;       // 16-lane group: k-block for A/B, row-block for C
    const int er = lane & 15;      // A: edge row within tile; B/C: channel col

    // B fragments (W in f16, K padded to 160), built once from L1-resident Wk/bk.
    // Same assumed k-map as A-frag generation => correctness is k-map-invariant.
    half8v bfr[5];
#pragma unroll
    for (int fr = 0; fr < 5; ++fr) {
#pragma unroll
        for (int j = 0; j < 8; ++j) {
            int k = fr * 32 + g * 8 + j;
            float w = 0.f;
            if (k < S * F) w = Wk[k * H + er];
            else if (k < S * F + F) w = bk[(k - S * F) * H + er];
            bfr[fr][j] = (_Float16)w;
        }
    }

    const int TILES = (E + 15) >> 4;
    int wid = blockIdx.x * (blockDim.x >> 6) + (threadIdx.x >> 6);
    int wstride = gridDim.x * (blockDim.x >> 6);

    for (int t = wid; t < TILES; t += wstride) {
        int e0 = t << 4;
        int eA = min(e0 + er, E - 1);  // clamp loads; scatter is guarded below
        int sn = __builtin_nontemporal_load(src + eA);

        // this lane's x half-row: f0 = (g&1)*8, invariant across all 5 frags
        const vf4* xp = (const vf4*)(x + (size_t)sn * F + (g & 1) * 8);
        vf4 xa = xp[0], xb = xp[1];
        float xh[8] = {xa.x, xa.y, xa.z, xa.w, xb.x, xb.y, xb.z, xb.w};

        f32x4 acc = {0.f, 0.f, 0.f, 0.f};
#pragma unroll
        for (int fr = 0; fr < 4; ++fr) {
            // lane's k-block = fr*32 + g*8  ->  s = fr*2 + (g>>1)
            float es = __builtin_nontemporal_load(
                efeat + (size_t)eA * S + fr * 2 + (g >> 1));
            half8v a;
#pragma unroll
            for (int j = 0; j < 8; ++j) a[j] = (_Float16)(es * xh[j]);
            acc = __builtin_amdgcn_mfma_f32_16x16x32_f16(a, bfr[fr], acc, 0, 0, 0);
        }
        {   // bias frag: k in [128,144) coeff 1.0 (g<2), k in [144,160) zero pad
            half8v a;
#pragma unroll
            for (int j = 0; j < 8; ++j)
                a[j] = (g < 2) ? (_Float16)xh[j] : (_Float16)0.f;
            acc = __builtin_amdgcn_mfma_f32_16x16x32_f16(a, bfr[4], acc, 0, 0, 0);
        }

        // C[row = g*4+r][col = er] -> coalesced atomic scatter
#pragma unroll
        for (int r = 0; r < 4; ++r) {
            int ei = e0 + g * 4 + r;
            if (ei < E) {
                int dn = dst[ei];
                unsafeAtomicAdd(&agg[(size_t)dn * H + er], acc[r]);
            }
        }
    }
}

// Kernel 2: h = BN(relu(agg_edges + x@Wr + br)); per-channel global max.
// Thread handles one (node, 4-channel) quarter: float4 agg load + 64 FMA base.
template <int F, int H>
__global__ void __launch_bounds__(256)
base_bn_relu_max(const float* __restrict__ agg,
                 const float* __restrict__ x,
                 const float* __restrict__ Wr,
                 const float* __restrict__ br,
                 const float* __restrict__ gamma,
                 const float* __restrict__ beta,
                 const float* __restrict__ mmean,
                 const float* __restrict__ mvar,
                 unsigned int* __restrict__ pooled_u,
                 int N) {
    __shared__ unsigned int smax[H];
    if (threadIdx.x < H) smax[threadIdx.x] = 0u;
    __syncthreads();

    int i = blockIdx.x * blockDim.x + threadIdx.x;   // (n, quarter)
    int h4 = (i & 3) * 4;
    float best[4] = {-INFINITY, -INFINITY, -INFINITY, -INFINITY};
    if (i < N * 4) {
        int n = i >> 2;
        const vf4* xr = (const vf4*)(x + (size_t)n * F);
        vf4 x0 = xr[0], x1 = xr[1], x2 = xr[2], x3 = xr[3];
        float xf[16] = {x0.x, x0.y, x0.z, x0.w, x1.x, x1.y, x1.z, x1.w,
                        x2.x, x2.y, x2.z, x2.w, x3.x, x3.y, x3.z, x3.w};
        vf4 a = ((const vf4*)agg)[i];
#pragma unroll
        for (int j = 0; j < 4; ++j) {
            int h = h4 + j;
            float base = br[h];
#pragma unroll
            for (int f = 0; f < F; ++f) base += xf[f] * Wr[f * H + h];
            float w = a[j] + base;
            w = w > 0.f ? w : 0.f;                       // relu
            float s = gamma[h] * rsqrtf(mvar[h] + BN_EPS);
            w = w * s + (beta[h] - mmean[h] * s);        // BN (inference)
            best[j] = fmaxf(best[j], w);
        }
    }
#pragma unroll
    for (int j = 0; j < 4; ++j) atomicMax(&smax[h4 + j], f2k(best[j]));
    __syncthreads();
    if (threadIdx.x < H) atomicMax(&pooled_u[threadIdx.x], smax[threadIdx.x]);
}

// Kernel 3: out[j] = bd[j] + sum_h pooled[h] * Wd[h,j]
template <int H>
__global__ void final_matvec(const unsigned int* __restrict__ pooled_u,
                             const float* __restrict__ Wd,
                             const float* __restrict__ bd,
                             float* __restrict__ out,
                             int HOUT) {
    int j = threadIdx.x;
    if (j >= HOUT) return;
    float acc = bd[j];
#pragma unroll
    for (int hh = 0; hh < H; ++hh) acc += k2f(pooled_u[hh]) * Wd[hh * HOUT + j];
    out[j] = acc;
}

extern "C" void kernel_launch(void* const* d_in, const int* in_sizes, int n_in,
                              void* d_out, int out_size, void* d_ws, size_t ws_size,
                              hipStream_t stream) {
    const float* x     = (const float*)d_in[0];
    const float* e     = (const float*)d_in[1];
    const int*   src   = (const int*)d_in[2];
    const int*   dst   = (const int*)d_in[3];
    const float* Wk    = (const float*)d_in[4];
    const float* bk    = (const float*)d_in[5];
    const float* Wr    = (const float*)d_in[6];
    const float* br    = (const float*)d_in[7];
    const float* gamma = (const float*)d_in[8];
    const float* beta  = (const float*)d_in[9];
    const float* mmean = (const float*)d_in[10];
    const float* mvar  = (const float*)d_in[11];
    const float* Wd    = (const float*)d_in[12];
    const float* bd    = (const float*)d_in[13];

    constexpr int S = 8, F = 16, H = 16;
    const int E = in_sizes[2];
    const int N = in_sizes[0] / F;
    const int HOUT = in_sizes[13];  // 3

    // workspace: agg [N,H] fp32, then pooled_u [H]
    float* agg = (float*)d_ws;
    unsigned int* pooled_u = (unsigned int*)(agg + (size_t)N * H);

    // zero agg + pooled keys in one stream-ordered (capturable) memset
    hipMemsetAsync(d_ws, 0, (size_t)N * H * sizeof(float) + H * sizeof(unsigned int),
                   stream);

    const int T = 256;
    int TILES = (E + 15) / 16;
    int eblocks = (TILES + 15) / 16;        // 4 waves/block, ~4 tiles/wave
    edge_mfma<S, F, H><<<eblocks, T, 0, stream>>>(e, src, dst, x, Wk, bk, agg, E);

    int bblocks = (N * 4 + T - 1) / T;
    base_bn_relu_max<F, H><<<bblocks, T, 0, stream>>>(
        agg, x, Wr, br, gamma, beta, mmean, mvar, pooled_u, N);

    final_matvec<H><<<1, 64, 0, stream>>>(pooled_u, Wd, bd, (float*)d_out, HOUT);
}